// Round 7
// baseline (390.279 us; speedup 1.0000x reference)
//
#include <hip/hip_runtime.h>
#include <hip/hip_fp16.h>

#define INF    256
#define OUTF   64
#define TSH    5          // log2(nodes per bucket)
#define TNODE  32         // nodes per bucket
#define NBMAX  1600       // max buckets (50016/32 = 1563)
#define MS_T   512        // msplit block size
#define MS_EPT 8          // msplit edges per thread

typedef __attribute__((ext_vector_type(8))) short bf16x8;
typedef __attribute__((ext_vector_type(4))) float f32x4;

__device__ __forceinline__ short f2bf(float f) {
    union { float f; unsigned int u; } v; v.f = f;
    unsigned int u = v.u;
    u += 0x7FFFu + ((u >> 16) & 1u);   // round-to-nearest-even
    return (short)(u >> 16);
}

// ---------------- histogram: cnt[d] = #incoming edges (int4-vectorized) ----------------
__global__ void hist_kernel(const int* __restrict__ dst, int* __restrict__ cnt, int e) {
    int i = (blockIdx.x * blockDim.x + threadIdx.x) * 4;
    if (i + 3 < e) {
        int4 d = *reinterpret_cast<const int4*>(dst + i);
        atomicAdd(&cnt[d.x], 1);
        atomicAdd(&cnt[d.y], 1);
        atomicAdd(&cnt[d.z], 1);
        atomicAdd(&cnt[d.w], 1);
    } else {
        for (; i < e; ++i) atomicAdd(&cnt[dst[i]], 1);
    }
}

// ---------------- bucket_scan: single block; bucket sums -> exclusive scan -> bptr/gcur ----
__global__ __launch_bounds__(1024) void bucket_scan_kernel(
    const int* __restrict__ cnt, int* __restrict__ gcur, int* __restrict__ bptr, int nbuck)
{
    __shared__ int s[1024];
    const int t = threadIdx.x;
    const int b0 = 2 * t, b1 = 2 * t + 1;
    int c0 = 0, c1 = 0;
    if (b0 < nbuck) {
        const int4* p = reinterpret_cast<const int4*>(cnt + (b0 << TSH));
        #pragma unroll
        for (int k = 0; k < 8; ++k) { int4 v = p[k]; c0 += v.x + v.y + v.z + v.w; }
    }
    if (b1 < nbuck) {
        const int4* p = reinterpret_cast<const int4*>(cnt + (b1 << TSH));
        #pragma unroll
        for (int k = 0; k < 8; ++k) { int4 v = p[k]; c1 += v.x + v.y + v.z + v.w; }
    }
    int tot = c0 + c1;
    s[t] = tot;
    __syncthreads();
    #pragma unroll
    for (int off = 1; off < 1024; off <<= 1) {
        int add = (t >= off) ? s[t - off] : 0;
        __syncthreads();
        s[t] += add;
        __syncthreads();
    }
    int excl = s[t] - tot;
    if (b0 < nbuck) { gcur[b0] = excl;      bptr[b0] = excl; }
    if (b1 < nbuck) { gcur[b1] = excl + c0; bptr[b1] = excl + c0; }
    if (t == 1023) bptr[nbuck] = s[1023];   // == e
}

// ---------------- msplit: bucket edges by dst>>TSH, dense chunked writes ----------------
// packed word: (src & 0xFFFF) | (dst_local << 16)   [n=50000 < 65536, dl < 32]
__global__ __launch_bounds__(MS_T) void msplit_kernel(
    const int* __restrict__ src, const int* __restrict__ dst,
    int* __restrict__ gcur, int* __restrict__ ebuk, int e, int nbuck)
{
    __shared__ int h[NBMAX], lb[NBMAX];
    const int t = threadIdx.x;
    for (int i = t; i < nbuck; i += MS_T) h[i] = 0;
    __syncthreads();

    const int base = blockIdx.x * (MS_T * MS_EPT);
    int sv[MS_EPT], dl[MS_EPT], off[MS_EPT], bk[MS_EPT];
    #pragma unroll
    for (int k = 0; k < MS_EPT; ++k) {
        int i = base + k * MS_T + t;
        if (i < e) {
            int ss = src[i], dd = dst[i];
            sv[k] = ss; bk[k] = dd >> TSH; dl[k] = dd & (TNODE - 1);
            off[k] = atomicAdd(&h[bk[k]], 1);
        } else bk[k] = -1;
    }
    __syncthreads();
    for (int i = t; i < nbuck; i += MS_T) lb[i] = atomicAdd(&gcur[i], h[i]);
    __syncthreads();
    #pragma unroll
    for (int k = 0; k < MS_EPT; ++k) {
        if (bk[k] >= 0)
            ebuk[lb[bk[k]] + off[k]] = (sv[k] & 0xFFFF) | (dl[k] << 16);
    }
}

// ---------------- GEMM (MFMA bf16): hp16 = fp16( (x@W) * rsqrt(cnt+1) ) ----------------
__global__ __launch_bounds__(256, 2) void gemm_mfma_kernel(
    const float* __restrict__ x, const float* __restrict__ W,
    const int* __restrict__ cnt, __half* __restrict__ hp16,
    int n, int ntiles, int wstride)
{
    const int lane = threadIdx.x & 63;
    const int wid  = blockIdx.x * 4 + (threadIdx.x >> 6);
    const int lg   = lane >> 4;      // k-group 0..3
    const int lr   = lane & 15;      // A row / B col / C col (within tile)

    // B fragments: breg[ct][ks] elem j = bf16( W[ks*32 + lg*8 + j][ct*16 + lr] )
    bf16x8 breg[4][8];
    #pragma unroll
    for (int ct = 0; ct < 4; ++ct) {
        #pragma unroll
        for (int ks = 0; ks < 8; ++ks) {
            const float* wp = W + (size_t)(ks * 32 + lg * 8) * OUTF + ct * 16 + lr;
            bf16x8 f;
            #pragma unroll
            for (int j = 0; j < 8; ++j)
                f[j] = f2bf(wp[(size_t)j * OUTF]);
            breg[ct][ks] = f;
        }
    }

    for (int t = wid; t < ntiles; t += wstride) {
        const int r0 = t * 16;
        const int arow = min(r0 + lr, n - 1);
        const float* xr = x + (size_t)arow * INF;

        float4 araw[16];
        #pragma unroll
        for (int ks = 0; ks < 8; ++ks) {
            const float4* xp = reinterpret_cast<const float4*>(xr + ks * 32 + lg * 8);
            araw[2 * ks]     = xp[0];
            araw[2 * ks + 1] = xp[1];
        }

        f32x4 acc0 = {0,0,0,0}, acc1 = {0,0,0,0}, acc2 = {0,0,0,0}, acc3 = {0,0,0,0};
        #pragma unroll
        for (int ks = 0; ks < 8; ++ks) {
            float4 a0 = araw[2 * ks], a1 = araw[2 * ks + 1];
            bf16x8 af;
            af[0] = f2bf(a0.x); af[1] = f2bf(a0.y); af[2] = f2bf(a0.z); af[3] = f2bf(a0.w);
            af[4] = f2bf(a1.x); af[5] = f2bf(a1.y); af[6] = f2bf(a1.z); af[7] = f2bf(a1.w);
            acc0 = __builtin_amdgcn_mfma_f32_16x16x32_bf16(af, breg[0][ks], acc0, 0, 0, 0);
            acc1 = __builtin_amdgcn_mfma_f32_16x16x32_bf16(af, breg[1][ks], acc1, 0, 0, 0);
            acc2 = __builtin_amdgcn_mfma_f32_16x16x32_bf16(af, breg[2][ks], acc2, 0, 0, 0);
            acc3 = __builtin_amdgcn_mfma_f32_16x16x32_bf16(af, breg[3][ks], acc3, 0, 0, 0);
        }

        // C/D: row = r0 + lg*4 + reg, col = ct*16 + lr   [m89-verified mapping]
        #pragma unroll
        for (int reg = 0; reg < 4; ++reg) {
            int row = r0 + lg * 4 + reg;
            if (row < n) {
                float di = rsqrtf((float)(cnt[row] + 1));
                __half* op = hp16 + (size_t)row * OUTF + lr;
                op[0]  = __float2half(acc0[reg] * di);
                op[16] = __float2half(acc1[reg] * di);
                op[32] = __float2half(acc2[reg] * di);
                op[48] = __float2half(acc3[reg] * di);
            }
        }
    }
}

// ---------------- bucket aggregate: LDS accumulators, fused bias+relu ----------------
// One block per 32-node bucket. accum[32][64] f32 in LDS, init = self-loop hp';
// stream bucketed edges: gather hp'[src] (128 B), LDS atomicAdd into accum[dst_local];
// epilogue: out = relu(accum * rsqrt(cnt+1) + b), dense write.
__global__ __launch_bounds__(256) void bucket_agg_kernel(
    const int* __restrict__ bptr, const int* __restrict__ ebuk,
    const int* __restrict__ cnt, const __half2* __restrict__ hp2,
    const float* __restrict__ b, float* __restrict__ out, int n)
{
    __shared__ float accum[TNODE][OUTF];   // 8 KB
    __shared__ float sdi[TNODE];

    const int bkt = blockIdx.x;
    const int t   = threadIdx.x;
    const int nb0 = bkt << TSH;
    const int nn  = min(TNODE, n - nb0);
    const int hw  = t >> 5;      // half-wave 0..7
    const int l   = t & 31;      // feature pair

    // init accum with self-loop term hp'[node]
    for (int i = hw; i < TNODE; i += 8) {
        if (i < nn) {
            float2 v = __half22float2(hp2[(size_t)(nb0 + i) * 32 + l]);
            accum[i][2 * l]     = v.x;
            accum[i][2 * l + 1] = v.y;
        }
    }
    if (t < TNODE) sdi[t] = (t < nn) ? rsqrtf((float)(cnt[nb0 + t] + 1)) : 0.f;
    __syncthreads();

    const int beg = bptr[bkt];
    const int end = bptr[bkt + 1];

    int j = beg + hw;
    // 2-deep pipeline per half-wave -> 16 gathers in flight per block
    for (; j + 8 < end; j += 16) {
        int p0 = ebuk[j];
        int p1 = ebuk[j + 8];
        int s0 = p0 & 0xFFFF, d0 = (p0 >> 16) & (TNODE - 1);
        int s1 = p1 & 0xFFFF, d1 = (p1 >> 16) & (TNODE - 1);
        float2 v0 = __half22float2(hp2[(size_t)s0 * 32 + l]);
        float2 v1 = __half22float2(hp2[(size_t)s1 * 32 + l]);
        atomicAdd(&accum[d0][2 * l],     v0.x);
        atomicAdd(&accum[d0][2 * l + 1], v0.y);
        atomicAdd(&accum[d1][2 * l],     v1.x);
        atomicAdd(&accum[d1][2 * l + 1], v1.y);
    }
    for (; j < end; j += 8) {
        int p = ebuk[j];
        int s = p & 0xFFFF, d = (p >> 16) & (TNODE - 1);
        float2 v = __half22float2(hp2[(size_t)s * 32 + l]);
        atomicAdd(&accum[d][2 * l],     v.x);
        atomicAdd(&accum[d][2 * l + 1], v.y);
    }
    __syncthreads();

    // epilogue: dense write with bias + relu
    float2 bb = reinterpret_cast<const float2*>(b)[l];
    for (int i = hw; i < nn; i += 8) {
        float di = sdi[i];
        float ox = fmaxf(accum[i][2 * l]     * di + bb.x, 0.f);
        float oy = fmaxf(accum[i][2 * l + 1] * di + bb.y, 0.f);
        reinterpret_cast<float2*>(out)[(size_t)(nb0 + i) * 32 + l] = make_float2(ox, oy);
    }
}

extern "C" void kernel_launch(void* const* d_in, const int* in_sizes, int n_in,
                              void* d_out, int out_size, void* d_ws, size_t ws_size,
                              hipStream_t stream) {
    const float* x    = (const float*)d_in[0];
    const int*   edge = (const int*)d_in[1];
    const float* W    = (const float*)d_in[2];
    const float* b    = (const float*)d_in[3];
    float* out = (float*)d_out;

    const int n = in_sizes[0] / INF;   // 50000
    const int e = in_sizes[1] / 2;     // 800000
    const int* src = edge;
    const int* dst = edge + e;
    const int nbuck = (n + TNODE - 1) >> TSH;        // 1563
    const int npad  = nbuck << TSH;                  // 50016 (pad cnt to bucket multiple)

    // workspace layout
    char* wsc = (char*)d_ws;
    size_t off = 0;
    auto alloc = [&](size_t bytes) { char* p = wsc + off; off += (bytes + 511) & ~511ull; return p; };
    int*    cnt  = (int*)   alloc((size_t)npad * 4);
    int*    bptr = (int*)   alloc((size_t)(nbuck + 1) * 4);
    int*    gcur = (int*)   alloc((size_t)nbuck * 4);
    int*    ebuk = (int*)   alloc((size_t)e * 4);
    __half* hp16 = (__half*)alloc((size_t)n * OUTF * 2);

    // 1) zero cnt (memset node in graph), histogram
    hipMemsetAsync(cnt, 0, (size_t)npad * 4, stream);
    {
        int e4 = (e + 3) / 4;
        hist_kernel<<<(e4 + 255) / 256, 256, 0, stream>>>(dst, cnt, e);
    }

    // 2) single-block scan over bucket sums -> bptr, gcur
    bucket_scan_kernel<<<1, 1024, 0, stream>>>(cnt, gcur, bptr, nbuck);

    // 3) bucket edges (dense chunked writes)
    {
        int blocks = (e + MS_T * MS_EPT - 1) / (MS_T * MS_EPT);   // 196
        msplit_kernel<<<blocks, MS_T, 0, stream>>>(src, dst, gcur, ebuk, e, nbuck);
    }

    // 4) GEMM (MFMA): hp16 = fp16((x@W)*rsqrt(cnt+1))
    {
        const int ntiles = (n + 15) / 16;       // 3125
        const int blocks = 512;                 // 2048 waves
        gemm_mfma_kernel<<<blocks, 256, 0, stream>>>(x, W, cnt, hp16, n, ntiles, blocks * 4);
    }

    // 5) bucket aggregate + bias + relu
    bucket_agg_kernel<<<nbuck, 256, 0, stream>>>(bptr, ebuk, cnt,
        reinterpret_cast<const __half2*>(hp16), b, out, n);
}

// Round 8
// 146.612 us; speedup vs baseline: 2.6620x; 2.6620x over previous
//
#include <hip/hip_runtime.h>
#include <hip/hip_fp16.h>

#define INF    256
#define OUTF   64
#define TSH    7          // log2(nodes per bucket)
#define TNODE  128        // nodes per bucket
#define PCAP   8192       // bucket_place LDS staging capacity (edges)
#define MS_T   512        // msplit block size
#define MS_EPT 8          // msplit edges per thread
#define NBMAX  512        // max buckets (50048/128 = 391)
#define CH     52         // scan chunk per thread (1024*52 = 53248 >= 50048)

typedef __attribute__((ext_vector_type(8))) short bf16x8;
typedef __attribute__((ext_vector_type(4))) float f32x4;

__device__ __forceinline__ short f2bf(float f) {
    union { float f; unsigned int u; } v; v.f = f;
    unsigned int u = v.u;
    u += 0x7FFFu + ((u >> 16) & 1u);   // round-to-nearest-even
    return (short)(u >> 16);
}

// ---------------- histogram: cnt[d] = #incoming edges (int4-vectorized) ----------------
__global__ void hist_kernel(const int* __restrict__ dst, int* __restrict__ cnt, int e) {
    int i = (blockIdx.x * blockDim.x + threadIdx.x) * 4;
    if (i + 3 < e) {
        int4 d = *reinterpret_cast<const int4*>(dst + i);
        atomicAdd(&cnt[d.x], 1);
        atomicAdd(&cnt[d.y], 1);
        atomicAdd(&cnt[d.z], 1);
        atomicAdd(&cnt[d.w], 1);
    } else {
        for (; i < e; ++i) atomicAdd(&cnt[dst[i]], 1);
    }
}

// ---------------- fused single-block scan: cnt -> rowptr (exclusive) + gcur ----------------
// 1024 threads, each owns CH=52 consecutive nodes in registers; Hillis-Steele block scan.
__global__ __launch_bounds__(1024) void scan_fused_kernel(
    const int* __restrict__ cnt, int* __restrict__ rowptr,
    int* __restrict__ gcur, int n, int nbuck)
{
    __shared__ int s[1024];
    const int t = threadIdx.x;
    const int g0 = t * CH;
    int v[CH];
    int tot = 0;
    #pragma unroll
    for (int k = 0; k < CH; k += 4) {
        int4 q = *reinterpret_cast<const int4*>(cnt + g0 + k);
        v[k] = q.x; v[k + 1] = q.y; v[k + 2] = q.z; v[k + 3] = q.w;
        tot += q.x + q.y + q.z + q.w;
    }
    s[t] = tot;
    __syncthreads();
    for (int off = 1; off < 1024; off <<= 1) {
        int add = (t >= off) ? s[t - off] : 0;
        __syncthreads();
        s[t] += add;
        __syncthreads();
    }
    int run = s[t] - tot;   // exclusive prefix of this thread's chunk
    #pragma unroll
    for (int k = 0; k < CH; ++k) {
        int g = g0 + k;
        if (g <= n) rowptr[g] = run;
        if ((g & (TNODE - 1)) == 0 && (g >> TSH) < nbuck) gcur[g >> TSH] = run;
        run += v[k];
    }
}

// ---------------- msplit: bucket edges by dst>>TSH, dense chunked writes ----------------
// packed word: (src & 0xFFFF) | (dst_local << 16)
__global__ __launch_bounds__(MS_T) void msplit_kernel(
    const int* __restrict__ src, const int* __restrict__ dst,
    int* __restrict__ gcur, int* __restrict__ ebuk, int e, int nbuck)
{
    __shared__ int h[NBMAX], lb[NBMAX];
    const int t = threadIdx.x;
    for (int i = t; i < nbuck; i += MS_T) h[i] = 0;
    __syncthreads();

    const int base = blockIdx.x * (MS_T * MS_EPT);
    int sv[MS_EPT], dl[MS_EPT], off[MS_EPT], bk[MS_EPT];
    #pragma unroll
    for (int k = 0; k < MS_EPT; ++k) {
        int i = base + k * MS_T + t;
        if (i < e) {
            int ss = src[i], dd = dst[i];
            sv[k] = ss; bk[k] = dd >> TSH; dl[k] = dd & (TNODE - 1);
            off[k] = atomicAdd(&h[bk[k]], 1);
        } else bk[k] = -1;
    }
    __syncthreads();
    for (int i = t; i < nbuck; i += MS_T) lb[i] = atomicAdd(&gcur[i], h[i]);
    __syncthreads();
    #pragma unroll
    for (int k = 0; k < MS_EPT; ++k) {
        if (bk[k] >= 0)
            ebuk[lb[bk[k]] + off[k]] = (sv[k] & 0xFFFF) | (dl[k] << 16);
    }
}

// ---------------- bucket_place: exact per-node CSR placement within bucket ----------------
__global__ __launch_bounds__(256) void bucket_place_kernel(
    const int* __restrict__ rowptr, const int* __restrict__ cnt,
    const int* __restrict__ ebuk, unsigned short* __restrict__ ecol, int n)
{
    __shared__ int sc[TNODE];
    __shared__ int lcur[TNODE];
    __shared__ unsigned short outb[PCAP];   // 16 KB

    const int b = blockIdx.x;
    const int t = threadIdx.x;
    const int nb0 = b << TSH;
    const int nn = min(TNODE, n - nb0);
    const int beg = rowptr[nb0];
    const int end = rowptr[nb0 + nn];
    const int m = end - beg;

    int v = (t < nn) ? cnt[nb0 + t] : 0;
    if (t < TNODE) sc[t] = v;
    __syncthreads();
    #pragma unroll
    for (int o = 1; o < TNODE; o <<= 1) {
        int add = (t < TNODE && t >= o) ? sc[t - o] : 0;
        __syncthreads();
        if (t < TNODE) sc[t] += add;
        __syncthreads();
    }
    if (t < TNODE) lcur[t] = sc[t] - v;
    __syncthreads();

    if (m <= PCAP) {
        for (int i = t; i < m; i += 256) {
            int p = ebuk[beg + i];
            int dlo = (p >> 16) & (TNODE - 1);
            int o = atomicAdd(&lcur[dlo], 1);
            outb[o] = (unsigned short)(p & 0xFFFF);
        }
        __syncthreads();
        for (int i = t; i < m; i += 256) ecol[beg + i] = outb[i];
    } else {
        for (int i = t; i < m; i += 256) {
            int p = ebuk[beg + i];
            int dlo = (p >> 16) & (TNODE - 1);
            int o = atomicAdd(&lcur[dlo], 1);
            ecol[beg + o] = (unsigned short)(p & 0xFFFF);
        }
    }
}

// ---------------- GEMM (MFMA bf16): hp16 = fp16( (x@W) * rsqrt(cnt+1) ) ----------------
__global__ __launch_bounds__(256, 2) void gemm_mfma_kernel(
    const float* __restrict__ x, const float* __restrict__ W,
    const int* __restrict__ cnt, __half* __restrict__ hp16,
    int n, int ntiles, int wstride)
{
    const int lane = threadIdx.x & 63;
    const int wid  = blockIdx.x * 4 + (threadIdx.x >> 6);
    const int lg   = lane >> 4;      // k-group 0..3
    const int lr   = lane & 15;      // A row / B col / C col (within tile)

    // B fragments: breg[ct][ks] elem j = bf16( W[ks*32 + lg*8 + j][ct*16 + lr] )
    bf16x8 breg[4][8];
    #pragma unroll
    for (int ct = 0; ct < 4; ++ct) {
        #pragma unroll
        for (int ks = 0; ks < 8; ++ks) {
            const float* wp = W + (size_t)(ks * 32 + lg * 8) * OUTF + ct * 16 + lr;
            bf16x8 f;
            #pragma unroll
            for (int j = 0; j < 8; ++j)
                f[j] = f2bf(wp[(size_t)j * OUTF]);
            breg[ct][ks] = f;
        }
    }

    for (int t = wid; t < ntiles; t += wstride) {
        const int r0 = t * 16;
        const int arow = min(r0 + lr, n - 1);
        const float* xr = x + (size_t)arow * INF;

        float4 araw[16];
        #pragma unroll
        for (int ks = 0; ks < 8; ++ks) {
            const float4* xp = reinterpret_cast<const float4*>(xr + ks * 32 + lg * 8);
            araw[2 * ks]     = xp[0];
            araw[2 * ks + 1] = xp[1];
        }

        f32x4 acc0 = {0,0,0,0}, acc1 = {0,0,0,0}, acc2 = {0,0,0,0}, acc3 = {0,0,0,0};
        #pragma unroll
        for (int ks = 0; ks < 8; ++ks) {
            float4 a0 = araw[2 * ks], a1 = araw[2 * ks + 1];
            bf16x8 af;
            af[0] = f2bf(a0.x); af[1] = f2bf(a0.y); af[2] = f2bf(a0.z); af[3] = f2bf(a0.w);
            af[4] = f2bf(a1.x); af[5] = f2bf(a1.y); af[6] = f2bf(a1.z); af[7] = f2bf(a1.w);
            acc0 = __builtin_amdgcn_mfma_f32_16x16x32_bf16(af, breg[0][ks], acc0, 0, 0, 0);
            acc1 = __builtin_amdgcn_mfma_f32_16x16x32_bf16(af, breg[1][ks], acc1, 0, 0, 0);
            acc2 = __builtin_amdgcn_mfma_f32_16x16x32_bf16(af, breg[2][ks], acc2, 0, 0, 0);
            acc3 = __builtin_amdgcn_mfma_f32_16x16x32_bf16(af, breg[3][ks], acc3, 0, 0, 0);
        }

        // C/D: row = r0 + lg*4 + reg, col = ct*16 + lr   [m89-verified mapping]
        #pragma unroll
        for (int reg = 0; reg < 4; ++reg) {
            int row = r0 + lg * 4 + reg;
            if (row < n) {
                float di = rsqrtf((float)(cnt[row] + 1));
                __half* op = hp16 + (size_t)row * OUTF + lr;
                op[0]  = __float2half(acc0[reg] * di);
                op[16] = __float2half(acc1[reg] * di);
                op[32] = __float2half(acc2[reg] * di);
                op[48] = __float2half(acc3[reg] * di);
            }
        }
    }
}

// ---------------- gather-aggregate + bias + relu (fp16 gathers, f32 accum) ----------------
// One wave per node; halves split edges by parity; 4 gathers in flight per half-wave.
__global__ __launch_bounds__(256) void aggregate_kernel(
    const int* __restrict__ rowptr, const unsigned short* __restrict__ ecol,
    const __half2* __restrict__ hp2, const int* __restrict__ cnt,
    const float* __restrict__ b, float* __restrict__ out, int n)
{
    int widx = (int)((blockIdx.x * (size_t)blockDim.x + threadIdx.x) >> 6);
    int lane = threadIdx.x & 63;
    int half = lane >> 5;
    int l    = lane & 31;
    if (widx >= n) return;

    float2 acc = make_float2(0.f, 0.f);
    if (half == 0) {
        float2 v = __half22float2(hp2[(size_t)widx * 32 + l]);   // self-loop term
        acc.x = v.x; acc.y = v.y;
    }

    int beg = rowptr[widx];
    int end = rowptr[widx + 1];

    int j = beg + half;
    // 4-deep pipeline per half-wave -> 8 gathers in flight per wave
    for (; j + 6 < end; j += 8) {
        int s0 = ecol[j];
        int s1 = ecol[j + 2];
        int s2 = ecol[j + 4];
        int s3 = ecol[j + 6];
        float2 v0 = __half22float2(hp2[(size_t)s0 * 32 + l]);
        float2 v1 = __half22float2(hp2[(size_t)s1 * 32 + l]);
        float2 v2 = __half22float2(hp2[(size_t)s2 * 32 + l]);
        float2 v3 = __half22float2(hp2[(size_t)s3 * 32 + l]);
        acc.x += v0.x + v1.x + v2.x + v3.x;
        acc.y += v0.y + v1.y + v2.y + v3.y;
    }
    for (; j < end; j += 2) {
        float2 v = __half22float2(hp2[(size_t)ecol[j] * 32 + l]);
        acc.x += v.x; acc.y += v.y;
    }

    float hx = __shfl(acc.x, lane | 32, 64);
    float hy = __shfl(acc.y, lane | 32, 64);
    if (half == 0) {
        float di = rsqrtf((float)(cnt[widx] + 1));
        float2 bb = reinterpret_cast<const float2*>(b)[l];
        float ox = fmaxf((acc.x + hx) * di + bb.x, 0.f);
        float oy = fmaxf((acc.y + hy) * di + bb.y, 0.f);
        reinterpret_cast<float2*>(out)[(size_t)widx * 32 + l] = make_float2(ox, oy);
    }
}

extern "C" void kernel_launch(void* const* d_in, const int* in_sizes, int n_in,
                              void* d_out, int out_size, void* d_ws, size_t ws_size,
                              hipStream_t stream) {
    const float* x    = (const float*)d_in[0];
    const int*   edge = (const int*)d_in[1];
    const float* W    = (const float*)d_in[2];
    const float* b    = (const float*)d_in[3];
    float* out = (float*)d_out;

    const int n = in_sizes[0] / INF;   // 50000
    const int e = in_sizes[1] / 2;     // 800000
    const int* src = edge;
    const int* dst = edge + e;
    const int nbuck = (n + TNODE - 1) >> TSH;        // 391
    const int npad  = 1024 * CH;                     // 53248 (scan coverage)

    // workspace layout
    char* wsc = (char*)d_ws;
    size_t off = 0;
    auto alloc = [&](size_t bytes) { char* p = wsc + off; off += (bytes + 511) & ~511ull; return p; };
    int*            cnt    = (int*)   alloc((size_t)npad * 4);
    int*            rowptr = (int*)   alloc((size_t)(n + 1) * 4);
    int*            gcur   = (int*)   alloc((size_t)nbuck * 4);
    int*            ebuk   = (int*)   alloc((size_t)e * 4);
    unsigned short* ecol   = (unsigned short*)alloc((size_t)e * 2);
    __half*         hp16   = (__half*)alloc((size_t)n * OUTF * 2);

    // 1) zero cnt, histogram
    hipMemsetAsync(cnt, 0, (size_t)npad * 4, stream);
    {
        int e4 = (e + 3) / 4;
        hist_kernel<<<(e4 + 255) / 256, 256, 0, stream>>>(dst, cnt, e);
    }

    // 2) fused single-block scan -> rowptr, gcur
    scan_fused_kernel<<<1, 1024, 0, stream>>>(cnt, rowptr, gcur, n, nbuck);

    // 3) bucket edges (dense chunked writes), then exact in-bucket placement
    {
        int blocks = (e + MS_T * MS_EPT - 1) / (MS_T * MS_EPT);   // 196
        msplit_kernel<<<blocks, MS_T, 0, stream>>>(src, dst, gcur, ebuk, e, nbuck);
    }
    bucket_place_kernel<<<nbuck, 256, 0, stream>>>(rowptr, cnt, ebuk, ecol, n);

    // 4) GEMM (MFMA): hp16 = fp16((x@W)*rsqrt(cnt+1))
    {
        const int ntiles = (n + 15) / 16;       // 3125
        const int blocks = 782;                 // 3128 waves -> 1 tile each
        gemm_mfma_kernel<<<blocks, 256, 0, stream>>>(x, W, cnt, hp16, n, ntiles, blocks * 4);
    }

    // 5) gather-aggregate + bias + relu
    aggregate_kernel<<<(n + 3) / 4, 256, 0, stream>>>(rowptr, ecol,
        reinterpret_cast<const __half2*>(hp16), cnt, b, out, n);
}